// Round 1
// baseline (67.681 us; speedup 1.0000x reference)
//
#include <hip/hip_runtime.h>

// Problem constants (match reference)
#define NCP   512
#define NOBS  256
#define NB    32
#define DY    3
#define PTS   16     // control points per block
#define GRP   16     // lanes (obstacle groups) per control point

// grad = LAM_S*sg/bs + LAM_C*cg/bs + LAM_F*fg ; out = -OPT_LR*grad
// KNOT_DT=0.1, CLEARANCE=0.5, MAX_VEL=3, MAX_ACC=6, a=1.5, b=-0.75

__global__ __launch_bounds__(256) void traj_grad_kernel(
    const float* __restrict__ cp,       // (B, NCP*3)
    const float* __restrict__ obs_loc,  // (B, NOBS, 3)
    const float* __restrict__ obs_size, // (B, NOBS, 3)
    const float* __restrict__ ref,      // (B, NCP, 3)
    float* __restrict__ out)            // (B, NCP*3)
{
    __shared__ float s_ox[NOBS], s_oy[NOBS], s_oz[NOBS];
    __shared__ float s_ia[NOBS], s_ib[NOBS], s_ic[NOBS];

    const int b   = blockIdx.y;
    const int tid = threadIdx.x;

    // ---- stage obstacles for this batch: loc + 1/size^2 (one obstacle/thread)
    {
        const int o = tid;  // 256 threads == NOBS
        const float* ol = obs_loc  + ((size_t)b * NOBS + o) * 3;
        const float* os = obs_size + ((size_t)b * NOBS + o) * 3;
        float ox = ol[0], oy = ol[1], oz = ol[2];
        float sx = os[0], sy = os[1], sz = os[2];
        s_ox[o] = ox; s_oy[o] = oy; s_oz[o] = oz;
        s_ia[o] = 1.0f / (sx * sx);
        s_ib[o] = 1.0f / (sy * sy);
        s_ic[o] = 1.0f / (sz * sz);
    }
    __syncthreads();

    const int p = tid >> 4;           // point slot within block [0,16)
    const int g = tid & (GRP - 1);    // obstacle group [0,16)
    const int i = blockIdx.x * PTS + p;

    const float* rp  = ref + ((size_t)b * NCP + i) * 3;
    const float  rx = rp[0], ry = rp[1], rz = rp[2];
    const float* cpi = cp + ((size_t)b * NCP + i) * 3;
    const float  cx = cpi[0], cy = cpi[1], cz = cpi[2];

    // ---- collision gradient: this lane covers obstacles [g*16, g*16+16)
    float gx = 0.0f, gy = 0.0f, gz = 0.0f;
    #pragma unroll
    for (int k = 0; k < 16; ++k) {
        // stagger start by g so the 16 distinct LDS addrs hit 16 distinct banks
        const int o = (g << 4) | ((k + g) & 15);
        const float ox = s_ox[o], oy = s_oy[o], oz = s_oz[o];
        const float dx = rx - ox, dy = ry - oy, dz = rz - oz;
        const float n2 = dx * dx + dy * dy + dz * dz;
        const float inv_n = rsqrtf(n2);
        const float ux = dx * inv_n, uy = dy * inv_n, uz = dz * inv_n;
        const float s  = ux * ux * s_ia[o] + uy * uy * s_ib[o] + uz * uz * s_ic[o];
        const float tt = rsqrtf(s);
        // dist = (cp - obs_loc).dir - tt   (dir is unit norm)
        const float dot = (cx - ox) * ux + (cy - oy) * uy + (cz - oz) * uz;
        const float de  = 0.5f - (dot - tt);
        const float coef = (de > 0.5f) ? (0.75f - 3.0f * de)
                         : ((de > 0.0f) ? (-3.0f * de * de) : 0.0f);
        gx = fmaf(coef, ux, gx);
        gy = fmaf(coef, uy, gy);
        gz = fmaf(coef, uz, gz);
    }

    // ---- reduce across the 16-lane group (stays within the wave)
    #pragma unroll
    for (int m = 1; m < GRP; m <<= 1) {
        gx += __shfl_xor(gx, m);
        gy += __shfl_xor(gy, m);
        gz += __shfl_xor(gz, m);
    }

    // ---- epilogue: lanes g=0,1,2 each handle one DY component of point i
    if (g < DY) {
        const int c = g;
        const float cgv = (c == 0) ? gx : ((c == 1) ? gy : gz);

        // cp[i-3 .. i+3][c], zero outside (zeros only used where terms are masked)
        float v[7];
        #pragma unroll
        for (int d = -3; d <= 3; ++d) {
            const int j = i + d;
            v[d + 3] = (j >= 0 && j < NCP) ? cp[((size_t)b * NCP + j) * 3 + c] : 0.0f;
        }

        // jerk J(j) = cp[j+3]-3cp[j+2]+3cp[j+1]-cp[j], valid 0<=j<=NCP-4
        auto Jv = [&](int j) -> float {
            if (j < 0 || j > NCP - 4) return 0.0f;
            const int x = j - i + 3;   // x in [0,3]
            return v[x + 3] - 3.0f * v[x + 2] + 3.0f * v[x + 1] - v[x];
        };
        const float sgv = -2.0f * Jv(i) + 6.0f * Jv(i - 1)
                        - 6.0f * Jv(i - 2) + 2.0f * Jv(i - 3);

        // velocity feasibility: gv(j) valid 0<=j<=NCP-2
        auto Gv = [&](int j) -> float {
            if (j < 0 || j > NCP - 2) return 0.0f;
            const int x = j - i + 3;
            const float velk = fabsf(v[x + 1] - v[x]) * 10.0f;   // |vel|/dt
            return (velk >= 3.0f) ? 20.0f * (velk - 3.0f) : 0.0f;
        };
        const float vfg = Gv(i - 1) - Gv(i);

        // acceleration feasibility: ga(j) valid 0<=j<=NCP-3
        auto Ga = [&](int j) -> float {
            if (j < 0 || j > NCP - 3) return 0.0f;
            const int x = j - i + 3;
            const float acck = fabsf(v[x + 2] - 2.0f * v[x + 1] + v[x]) * 100.0f;
            return (acck >= 6.0f) ? 200.0f * (acck - 6.0f) : 0.0f;
        };
        const float afg = Ga(i) - 2.0f * Ga(i - 1) + Ga(i - 2);

        const float fg = 100.0f * vfg + afg;   // vfg/dt^2 + afg

        const float grad = sgv * (1.0f / 32.0f)            // LAM_S * sg/bs
                         + 10.0f * (cgv * (1.0f / 32.0f))  // LAM_C * cg/bs
                         + fg;                             // LAM_F * fg
        out[((size_t)b * NCP + i) * 3 + c] = -0.01f * grad;
    }
}

extern "C" void kernel_launch(void* const* d_in, const int* in_sizes, int n_in,
                              void* d_out, int out_size, void* d_ws, size_t ws_size,
                              hipStream_t stream) {
    // dict order: t (unused), control_pts, obs_loc, obs_size, reference_pts
    const float* cp       = (const float*)d_in[1];
    const float* obs_loc  = (const float*)d_in[2];
    const float* obs_size = (const float*)d_in[3];
    const float* ref      = (const float*)d_in[4];
    float* out = (float*)d_out;

    dim3 grid(NCP / PTS, NB);   // (32, 32) = 1024 blocks
    dim3 block(256);
    traj_grad_kernel<<<grid, block, 0, stream>>>(cp, obs_loc, obs_size, ref, out);
}

// Round 5
// 67.047 us; speedup vs baseline: 1.0095x; 1.0095x over previous
//
#include <hip/hip_runtime.h>

// Problem constants (match reference)
#define NCP   512
#define NOBS  256
#define NB    32
// grad = LAM_S*sg/bs + LAM_C*cg/bs + LAM_F*fg ; out = -OPT_LR*grad
// KNOT_DT=0.1, CLEARANCE=0.5, MAX_VEL=3, MAX_ACC=6, a=1.5, b=-0.75

// Broadcast one lane's float to all lanes (SGPR) — lane is compile-time after unroll.
__device__ __forceinline__ float rl(float v, int lane) {
    return __int_as_float(__builtin_amdgcn_readlane(__float_as_int(v), lane));
}

// Block = 512 threads = 8 waves. Each wave: same 64 control points, its own
// 32-obstacle chunk. Obstacle data lives in lane-VGPRs, broadcast by readlane
// -> zero LDS traffic in the hot loop. One LDS pass reduces the 8 partials.
__global__ __launch_bounds__(512) void traj_grad_kernel(
    const float* __restrict__ cp,       // (B, NCP*3)
    const float* __restrict__ obs_loc,  // (B, NOBS, 3)
    const float* __restrict__ obs_size, // (B, NOBS, 3)
    const float* __restrict__ ref,      // (B, NCP, 3)
    float* __restrict__ out)            // (B, NCP*3)
{
    __shared__ float4 s_red[8][64];     // 8 KB partial collision grads

    const int b    = blockIdx.y;
    const int tid  = threadIdx.x;
    const int lane = tid & 63;
    const int wv   = tid >> 6;          // wave id = obstacle chunk [0,8)

    // ---- per-wave obstacle chunk into VGPRs (lanes 0..31 hold one obstacle each)
    float vox = 0.f, voy = 0.f, voz = 0.f, via = 1.f, vib = 1.f, vic = 1.f;
    {
        const int o = wv * 32 + lane;   // lane<32 only
        if (lane < 32) {
            const float* ol = obs_loc  + ((size_t)b * NOBS + o) * 3;
            const float* os = obs_size + ((size_t)b * NOBS + o) * 3;
            vox = ol[0]; voy = ol[1]; voz = ol[2];
            const float sx = os[0], sy = os[1], sz = os[2];
            via = 1.0f / (sx * sx);
            vib = 1.0f / (sy * sy);
            vic = 1.0f / (sz * sz);
        }
    }

    // ---- this thread's control point
    const int i = blockIdx.x * 64 + lane;
    const size_t base = ((size_t)b * NCP + i) * 3;
    const float rx = ref[base], ry = ref[base + 1], rz = ref[base + 2];
    const float cx = cp[base],  cy = cp[base + 1],  cz = cp[base + 2];
    const float ex = cx - rx,   ey = cy - ry,       ez = cz - rz;

    // ---- collision gradient over this wave's 32 obstacles
    float gx = 0.f, gy = 0.f, gz = 0.f;
    #pragma unroll
    for (int k = 0; k < 32; ++k) {
        const float ox = rl(vox, k), oy = rl(voy, k), oz = rl(voz, k);
        const float ia = rl(via, k), ib = rl(vib, k), ic = rl(vic, k);
        const float dx = rx - ox, dy = ry - oy, dz = rz - oz;
        const float dx2 = dx * dx, dy2 = dy * dy, dz2 = dz * dz;
        const float n2 = dx2 + dy2 + dz2;
        const float w  = fmaf(dz2, ic, fmaf(dy2, ib, dx2 * ia));
        const float inv_n = rsqrtf(n2);      // 1/|d|
        const float rq    = rsqrtf(w);       // independent of inv_n -> ILP
        const float ed = fmaf(ex, dx, fmaf(ey, dy, ez * dz));
        // dist = (cp-obs).u - tt = inv_n*(n2 + e.d) - n2*inv_n*rq
        const float inner = fmaf(-n2, rq, n2 + ed);
        const float dist  = inv_n * inner;
        float de = 0.5f - dist;
        de = fmaxf(de, 0.0f);
        const float m3  = -3.0f * de;
        const bool  far_ = de > 0.5f;
        const float t = far_ ? 1.0f  : de;    // quad: -3de^2 ; lin: 0.75-3de
        const float s = far_ ? 0.75f : 0.0f;
        const float coef = fmaf(m3, t, s);
        const float cf = coef * inv_n;        // coef * u = cf * d
        gx = fmaf(cf, dx, gx);
        gy = fmaf(cf, dy, gy);
        gz = fmaf(cf, dz, gz);
    }

    s_red[wv][lane] = make_float4(gx, gy, gz, 0.f);
    __syncthreads();

    // ---- epilogue: 3 waves, thread (c = tid>>6, p = tid&63) handles out[b][i][c]
    if (tid < 192) {
        const int c  = tid >> 6;
        const int p  = tid & 63;
        const int i2 = blockIdx.x * 64 + p;

        float cg = 0.f;
        #pragma unroll
        for (int w = 0; w < 8; ++w)
            cg += ((const float*)&s_red[w][p])[c];

        // cp[i-3 .. i+3][c], zero outside (only used where terms are masked)
        float v[7];
        #pragma unroll
        for (int d = -3; d <= 3; ++d) {
            const int j = i2 + d;
            v[d + 3] = (j >= 0 && j < NCP) ? cp[((size_t)b * NCP + j) * 3 + c] : 0.f;
        }

        // jerk J(j) = cp[j+3]-3cp[j+2]+3cp[j+1]-cp[j], valid 0<=j<=NCP-4
        auto Jv = [&](int j) -> float {
            if (j < 0 || j > NCP - 4) return 0.f;
            const int x = j - i2 + 3;   // [0,3]
            return v[x + 3] - 3.f * v[x + 2] + 3.f * v[x + 1] - v[x];
        };
        const float sgv = -2.f * Jv(i2) + 6.f * Jv(i2 - 1)
                        - 6.f * Jv(i2 - 2) + 2.f * Jv(i2 - 3);

        // velocity feasibility: gv(j) valid 0<=j<=NCP-2
        auto Gv = [&](int j) -> float {
            if (j < 0 || j > NCP - 2) return 0.f;
            const int x = j - i2 + 3;
            const float velk = fabsf(v[x + 1] - v[x]) * 10.f;
            return (velk >= 3.f) ? 20.f * (velk - 3.f) : 0.f;
        };
        const float vfg = Gv(i2 - 1) - Gv(i2);

        // acceleration feasibility: ga(j) valid 0<=j<=NCP-3
        auto Ga = [&](int j) -> float {
            if (j < 0 || j > NCP - 3) return 0.f;
            const int x = j - i2 + 3;
            const float acck = fabsf(v[x + 2] - 2.f * v[x + 1] + v[x]) * 100.f;
            return (acck >= 6.f) ? 200.f * (acck - 6.f) : 0.f;
        };
        const float afg = Ga(i2) - 2.f * Ga(i2 - 1) + Ga(i2 - 2);

        const float fg = 100.f * vfg + afg;   // vfg/dt^2 + afg

        const float grad = sgv * (1.f / 32.f)           // LAM_S * sg/bs
                         + 10.f * (cg * (1.f / 32.f))   // LAM_C * cg/bs
                         + fg;                          // LAM_F * fg
        out[((size_t)b * NCP + i2) * 3 + c] = -0.01f * grad;
    }
}

extern "C" void kernel_launch(void* const* d_in, const int* in_sizes, int n_in,
                              void* d_out, int out_size, void* d_ws, size_t ws_size,
                              hipStream_t stream) {
    // dict order: t (unused), control_pts, obs_loc, obs_size, reference_pts
    const float* cp       = (const float*)d_in[1];
    const float* obs_loc  = (const float*)d_in[2];
    const float* obs_size = (const float*)d_in[3];
    const float* ref      = (const float*)d_in[4];
    float* out = (float*)d_out;

    dim3 grid(NCP / 64, NB);   // (8, 32) = 256 blocks, 1 per CU
    dim3 block(512);           // 8 waves: 64 points x 8 obstacle chunks
    traj_grad_kernel<<<grid, block, 0, stream>>>(cp, obs_loc, obs_size, ref, out);
}